// Round 13
// baseline (370.728 us; speedup 1.0000x reference)
//
#include <hip/hip_runtime.h>
#include <hip/hip_bf16.h>
#include <stdint.h>

typedef __attribute__((ext_vector_type(8))) short short8;
typedef __attribute__((ext_vector_type(4))) float f32x4;

#define MFMA16(a, b, c) __builtin_amdgcn_mfma_f32_16x16x32_bf16(a, b, c, 0, 0, 0)

#define D_ 512
#define M_ 16384
#define SREF 2048
#define QT 64
#define KT 64
#define NT (SREF / KT)

#define VM0  asm volatile("s_waitcnt vmcnt(0)" ::: "memory")
#define LGKM0 asm volatile("s_waitcnt lgkmcnt(0)" ::: "memory")
#define BARRIER() do { asm volatile("s_waitcnt lgkmcnt(0)" ::: "memory"); \
                       __builtin_amdgcn_s_barrier(); \
                       asm volatile("" ::: "memory"); } while (0)

__device__ __forceinline__ ushort f2bf(float f) {
  union { float f; uint32_t u; } v; v.f = f;
  uint32_t r = v.u + 0x7fffu + ((v.u >> 16) & 1u);
  return (ushort)(r >> 16);
}

__device__ __forceinline__ void gld16(const void* g, void* l) {
  __builtin_amdgcn_global_load_lds(
      (const __attribute__((address_space(1))) void*)g,
      (__attribute__((address_space(3))) void*)l, 16, 0, 0);
}

// DPP cross-lane (VALU pipe): xor1 = quad_perm 0xB1, xor2 = 0x4E.
__device__ __forceinline__ float dppmax1(float v) {
  int x = __builtin_amdgcn_mov_dpp(__float_as_int(v), 0xB1, 0xF, 0xF, true);
  return fmaxf(v, __int_as_float(x));
}
__device__ __forceinline__ float dppmax2(float v) {
  int x = __builtin_amdgcn_mov_dpp(__float_as_int(v), 0x4E, 0xF, 0xF, true);
  return fmaxf(v, __int_as_float(x));
}
__device__ __forceinline__ float dppadd1(float v) {
  int x = __builtin_amdgcn_mov_dpp(__float_as_int(v), 0xB1, 0xF, 0xF, true);
  return v + __int_as_float(x);
}
__device__ __forceinline__ float dppadd2(float v) {
  int x = __builtin_amdgcn_mov_dpp(__float_as_int(v), 0x4E, 0xF, 0xF, true);
  return v + __int_as_float(x);
}

// ---------------- K0: W fp32 [k][n] -> bf16 W^T [z][n][k] ----------------
__global__ __launch_bounds__(256) void wprep_kernel(
    const float* __restrict__ Wq, const float* __restrict__ Wk,
    const float* __restrict__ Wv, ushort* __restrict__ Wt) {
  const int wb = blockIdx.x;  // 0..191 (z:3 x k0:8 x n0:8)
  const int z = wb >> 6;
  const int k0 = ((wb >> 3) & 7) * 64, n0 = (wb & 7) * 64;
  const float* W = (z == 0) ? Wq : ((z == 1) ? Wk : Wv);
  ushort* dst = Wt + (size_t)z * D_ * D_;
  __shared__ ushort T[64][72];
  const int r = threadIdx.x >> 3, c = (threadIdx.x & 7) * 8;
#pragma unroll
  for (int p = 0; p < 2; ++p) {
    int rr = p * 32 + r;
    const float* src = W + (size_t)(k0 + rr) * D_ + n0 + c;
    float4 a = *(const float4*)src;
    float4 b = *(const float4*)(src + 4);
    T[c + 0][rr] = f2bf(a.x); T[c + 1][rr] = f2bf(a.y);
    T[c + 2][rr] = f2bf(a.z); T[c + 3][rr] = f2bf(a.w);
    T[c + 4][rr] = f2bf(b.x); T[c + 5][rr] = f2bf(b.y);
    T[c + 6][rr] = f2bf(b.z); T[c + 7][rr] = f2bf(b.w);
  }
  __syncthreads();
#pragma unroll
  for (int p = 0; p < 2; ++p) {
    int rr = p * 32 + r;
    *(short8*)(dst + (size_t)(n0 + rr) * D_ + k0 + c) = *(const short8*)&T[rr][c];
  }
}

// ---------------- K1: fused QKV projection (3 GEMMs, one X pass) ---------
// Reads fp32 X directly (gld16-staged, XOR-swizzled chunks, converted to
// bf16 at fragment read). z=0: Q pre-scaled by 1/sqrt(512); z=1: K; z=2:
// V^T [b][d][s].
__global__ __launch_bounds__(256) void qkv_kernel(
    const float* __restrict__ X, const ushort* __restrict__ Wt,
    const float* __restrict__ bq, const float* __restrict__ bk,
    const float* __restrict__ bv, ushort* __restrict__ ws) {
  const int m0 = blockIdx.x * 64;
  const int n0 = blockIdx.y * 64;
  const int tid = threadIdx.x;
  const int lane = tid & 63;
  const int wid = tid >> 6;
  const int lr = lane & 15;
  const int lg = lane >> 4;
  const int m_base = (wid >> 1) * 32;
  const int n_base = (wid & 1) * 32;

  __shared__ union {
    struct { float Atf[64][32]; ushort Bt[3][64][32]; } s;  // 8K + 12K
    ushort bounce[64][72];
  } u;

  f32x4 acc[3][2][2] = {};
  const int l4r = lane >> 2, l4c = (lane & 3) * 8;

  for (int ks = 0; ks < 16; ++ks) {
    const int k0 = ks * 32;
    {  // stage A: f32, pre-swizzled source chunks (slot = chunk^(row&7))
      int rowl = lane >> 3, chunk = lane & 7;
#pragma unroll
      for (int i = 0; i < 2; ++i) {
        int r0 = wid * 16 + i * 8;
        int row = r0 + rowl;
        gld16(X + (size_t)(m0 + row) * D_ + k0 + ((chunk ^ (row & 7)) * 4),
              &u.s.Atf[r0][0]);
      }
    }
#pragma unroll
    for (int z = 0; z < 3; ++z)
      gld16(Wt + (size_t)z * D_ * D_ + (size_t)(n0 + wid * 16 + l4r) * D_ + k0 + l4c,
            &u.s.Bt[z][wid * 16][0]);
    __syncthreads();
    short8 a[2];
#pragma unroll
    for (int mf = 0; mf < 2; ++mf) {
      int row = m_base + mf * 16 + lr;
      const float* base = &u.s.Atf[row][0];
      int s0 = ((2 * lg) ^ (row & 7)) * 4;
      int s1 = ((2 * lg + 1) ^ (row & 7)) * 4;
      float4 lo = *(const float4*)(base + s0);
      float4 hi = *(const float4*)(base + s1);
      union { ushort u16[8]; short8 v; } pk;
      pk.u16[0] = f2bf(lo.x); pk.u16[1] = f2bf(lo.y);
      pk.u16[2] = f2bf(lo.z); pk.u16[3] = f2bf(lo.w);
      pk.u16[4] = f2bf(hi.x); pk.u16[5] = f2bf(hi.y);
      pk.u16[6] = f2bf(hi.z); pk.u16[7] = f2bf(hi.w);
      a[mf] = pk.v;
    }
#pragma unroll
    for (int z = 0; z < 3; ++z) {
#pragma unroll
      for (int nf = 0; nf < 2; ++nf) {
        short8 b = *(const short8*)&u.s.Bt[z][n_base + nf * 16 + lr][lg * 8];
#pragma unroll
        for (int mf = 0; mf < 2; ++mf)
          acc[z][mf][nf] = MFMA16(a[mf], b, acc[z][mf][nf]);
      }
    }
    __syncthreads();
  }

  const int b_idx = m0 >> 11;
  const int s0 = m0 & 2047;
  const float qscale = 0.04419417382415922f;  // 1/sqrt(512)
#pragma unroll
  for (int z = 0; z < 2; ++z) {
    const float* bias = (z == 0) ? bq : bk;
    ushort* outp = ws + (size_t)z * M_ * D_;
#pragma unroll
    for (int mf = 0; mf < 2; ++mf) {
#pragma unroll
      for (int nf = 0; nf < 2; ++nf) {
        int n = n0 + n_base + nf * 16 + lr;
        float bvv = bias[n];
        int mrow = m_base + mf * 16 + lg * 4;
#pragma unroll
        for (int r = 0; r < 4; ++r) {
          float v = acc[z][mf][nf][r] + bvv;
          if (z == 0) v *= qscale;
          outp[(size_t)(m0 + mrow + r) * D_ + n] = f2bf(v);
        }
      }
    }
  }
#pragma unroll
  for (int mf = 0; mf < 2; ++mf) {
#pragma unroll
    for (int nf = 0; nf < 2; ++nf) {
      int nloc = n_base + nf * 16 + lr;
      float bvv = bv[n0 + nloc];
      int mrow = m_base + mf * 16 + lg * 4;
      ushort4 st;
      st.x = f2bf(acc[2][mf][nf][0] + bvv);
      st.y = f2bf(acc[2][mf][nf][1] + bvv);
      st.z = f2bf(acc[2][mf][nf][2] + bvv);
      st.w = f2bf(acc[2][mf][nf][3] + bvv);
      *(ushort4*)&u.bounce[nloc][mrow] = st;
    }
  }
  __syncthreads();
  ushort* vout = ws + 2 * (size_t)M_ * D_;
  const int rr = tid >> 3, cc = (tid & 7) * 8;
#pragma unroll
  for (int p = 0; p < 2; ++p) {
    int d = p * 32 + rr;
    *(short8*)(vout + ((size_t)b_idx * 512 + n0 + d) * 2048 + s0 + cc) =
        *(const short8*)&u.bounce[d][cc];
  }
}

// ---------------- K2: flash attention, KT=64 + K reg-staged async --------
// r12 structure + T14 async-STAGE for K(t+1): global->reg at top of window
// A (full-window latency cover), reg->LDS (swizzled ds_write) after B2.
// VM0@B3 then drains only V(t) (long-issued) -> near-zero stall. Register
// footprint ~160 (kst +32); 2 waves/SIMD pinned; (512,4) spills (r6);
// qf[2][16] spills (r11).
__global__ __launch_bounds__(512, 2) void attn_kernel(
    const ushort* __restrict__ Qg, const ushort* __restrict__ Kg,
    const ushort* __restrict__ Vtg, float* __restrict__ Out) {
  const int b = blockIdx.y;
  const int q0 = blockIdx.x * QT;
  const int tid = threadIdx.x;
  const int lane = tid & 63;
  const int wid = tid >> 6;
  const int lr = lane & 15;
  const int lg = lane >> 4;
  const int mw = wid >> 1;   // 0..3  q-16-chunk (QK^T)
  const int nw = wid & 1;    // 0..1  kv-32-chunk (QK^T, 2 n-frags each)

  __shared__ __align__(16) ushort Ks[KT * 512];   // 64 KB, K rows XOR-swz
  __shared__ __align__(16) ushort Vs[512 * KT];   // 64 KB, V^T rows slot-swz
  __shared__ __align__(16) char  SsF[64 * 256];   // 16 KB, S f32, slot XOR row&7
  __shared__ __align__(16) char  PsB[64 * 128];   // 8 KB, P bf16, slot XOR row&7
  __shared__ float mstate[QT], lstate[QT], resc[QT];
  __shared__ int gflag[2];

  const ushort* Qrow = Qg + ((size_t)b * SREF + q0) * 512;
  const ushort* Krow = Kg + (size_t)b * SREF * 512;
  const ushort* Vrow = Vtg + (size_t)b * 512 * 2048;

  // Q A-frags: wave's 16 q-rows x D=512: 64 VGPRs
  short8 qf[16];
  {
    const ushort* qp = Qrow + (size_t)(mw * 16 + lr) * 512 + lg * 8;
#pragma unroll
    for (int ks = 0; ks < 16; ++ks) qf[ks] = *(const short8*)(qp + ks * 32);
  }
  if (tid < QT) { mstate[tid] = -1e30f; lstate[tid] = 0.0f; }

  f32x4 oacc[4][4] = {};
  short8 kst[8];   // K(t+1) staged in regs (wave's 8 rows), +32 VGPR

  auto issueK0 = [&]() {   // prologue only: DMA-stage K(0)
#pragma unroll
    for (int ii = 0; ii < 8; ++ii) {
      int r = wid * 8 + ii;
      gld16(Krow + (size_t)r * 512 + ((lane ^ (r & 7)) * 8), &Ks[r * 512]);
    }
  };
  auto loadKreg = [&](int t) {   // top of window A: global -> regs (linear)
#pragma unroll
    for (int ii = 0; ii < 8; ++ii) {
      int r = wid * 8 + ii;
      kst[ii] = *(const short8*)(Krow + (size_t)(t * KT + r) * 512 + lane * 8);
    }
  };
  auto writeKlds = [&]() {   // after B2: regs -> swizzled Ks slots
#pragma unroll
    for (int ii = 0; ii < 8; ++ii) {
      int r = wid * 8 + ii;
      *(short8*)((char*)Ks + r * 1024 + ((lane ^ (r & 7)) << 4)) = kst[ii];
    }
  };
  auto issueV = [&](int t) {
#pragma unroll
    for (int ii = 0; ii < 8; ++ii) {
      int i = wid * 8 + ii;              // 8 d-rows per instr; wave owns d-chunk
      int rloc = lane >> 3;              // 0..7
      int d = i * 8 + rloc;              // d&7 == rloc
      int cs = (lane & 7) ^ rloc;        // pre-swizzled col slot (16B units)
      gld16(Vrow + (size_t)d * 2048 + t * KT + cs * 8, &Vs[i * 512]);
    }
  };
  auto doPV = [&](int gf) {
    if (gf) {
#pragma unroll
      for (int mf = 0; mf < 4; ++mf) {
        f32x4 rv;
#pragma unroll
        for (int r = 0; r < 4; ++r) rv[r] = resc[mf * 16 + lg * 4 + r];
#pragma unroll
        for (int nf = 0; nf < 4; ++nf) oacc[mf][nf] *= rv;
      }
    }
#pragma unroll
    for (int kk = 0; kk < 2; ++kk) {
      short8 pA[4];
#pragma unroll
      for (int mf = 0; mf < 4; ++mf) {
        int row = mf * 16 + lr;
        pA[mf] = *(const short8*)(PsB + row * 128 + (((kk * 4 + lg) ^ (row & 7)) << 4));
      }
      __builtin_amdgcn_s_setprio(1);
#pragma unroll
      for (int nf = 0; nf < 4; ++nf) {
        int d = wid * 64 + nf * 16 + lr;
        short8 vB = *(const short8*)((const char*)Vs + d * 128 +
                                     (((kk * 4 + lg) ^ (d & 7)) << 4));
#pragma unroll
        for (int mf = 0; mf < 4; ++mf) oacc[mf][nf] = MFMA16(pA[mf], vB, oacc[mf][nf]);
      }
      __builtin_amdgcn_s_setprio(0);
    }
  };

  issueK0();
  VM0;        // prologue: K(0) landed
  BARRIER();  // all waves' K(0) staged + state init visible
  int gf = 0;

  for (int t = 0; t < NT; ++t) {
    const int cur = t & 1;
    // ---- window A: K(t+1) reg-load | PV(t-1) | V(t) issue | QK^T(t) ----
    if (t + 1 < NT) loadKreg(t + 1);   // latency covered by whole window A
    if (t > 0) {
      doPV(gf);   // reads Vs=V(t-1), PsB=P(t-1) — certified at B3(t-1)
      LGKM0;      // own V-row reads done before re-staging them
    }
    issueV(t);
    if (tid == 0) gflag[cur] = 0;
    {
      // QK^T: wave's 16 q-rows x 64 kv (2 n-frags); Q reused from regs
      f32x4 s0v = {0.f, 0.f, 0.f, 0.f}, s1v = {0.f, 0.f, 0.f, 0.f};
      const int krow = nw * 32 + lr;
      const char* kb0 = (const char*)Ks + krow * 1024;
      const char* kb1 = kb0 + 16 * 1024;   // krow+16: same XOR (16 = 0 mod 8)
      const int kx = (krow & 7) << 4;
      __builtin_amdgcn_s_setprio(1);
#pragma unroll
      for (int ks = 0; ks < 16; ++ks) {
        int off = (ks * 64 + lg * 16) ^ kx;
        short8 b0 = *(const short8*)(kb0 + off);
        short8 b1 = *(const short8*)(kb1 + off);
        s0v = MFMA16(qf[ks], b0, s0v);
        s1v = MFMA16(qf[ks], b1, s1v);
      }
      __builtin_amdgcn_s_setprio(0);
#pragma unroll
      for (int nf2 = 0; nf2 < 2; ++nf2) {
        f32x4 sv = (nf2 == 0) ? s0v : s1v;
        int c = nw * 32 + nf2 * 16 + lr;
#pragma unroll
        for (int r = 0; r < 4; ++r) {
          int row = mw * 16 + lg * 4 + r;
          *(float*)(SsF + row * 256 + ((((c >> 2) ^ (row & 7)) << 4) | ((c & 3) << 2))) = sv[r];
        }
      }
    }
    BARRIER();  // B2: S visible; Ks reads done; PsB reads (doPV) done

    // ---- window B: K(t+1) reg->LDS + softmax (defer-max THR=8) ----
    if (t + 1 < NT) writeKlds();     // Ks reads completed at B2
    {
      int row = tid >> 3, ic = tid & 7;
      float4 sa = *(const float4*)(SsF + row * 256 + ((((ic * 2) ^ (row & 7)) << 4)));
      float4 sb = *(const float4*)(SsF + row * 256 + ((((ic * 2 + 1) ^ (row & 7)) << 4)));
      float mx = fmaxf(fmaxf(fmaxf(sa.x, sa.y), fmaxf(sa.z, sa.w)),
                       fmaxf(fmaxf(sb.x, sb.y), fmaxf(sb.z, sb.w)));
      mx = dppmax1(mx); mx = dppmax2(mx); mx = fmaxf(mx, __shfl_xor(mx, 4));
      float mold = mstate[row];
      bool grow = (mx > mold + 8.0f);
      float mref = grow ? mx : mold;
      float p0 = __expf(sa.x - mref), p1 = __expf(sa.y - mref);
      float p2 = __expf(sa.z - mref), p3 = __expf(sa.w - mref);
      float p4 = __expf(sb.x - mref), p5 = __expf(sb.y - mref);
      float p6 = __expf(sb.z - mref), p7 = __expf(sb.w - mref);
      float psum = ((p0 + p1) + (p2 + p3)) + ((p4 + p5) + (p6 + p7));
      psum = dppadd1(psum); psum = dppadd2(psum); psum += __shfl_xor(psum, 4);
      union { ushort u[8]; short8 v; } pb;
      pb.u[0] = f2bf(p0); pb.u[1] = f2bf(p1); pb.u[2] = f2bf(p2); pb.u[3] = f2bf(p3);
      pb.u[4] = f2bf(p4); pb.u[5] = f2bf(p5); pb.u[6] = f2bf(p6); pb.u[7] = f2bf(p7);
      *(short8*)(PsB + row * 128 + ((ic ^ (row & 7)) << 4)) = pb.v;
      if (ic == 0) {
        float sc = grow ? __expf(mold - mx) : 1.0f;
        resc[row] = sc;
        lstate[row] = lstate[row] * sc + psum;
        if (grow) { mstate[row] = mx; gflag[cur] = 1; }
      }
    }
    VM0;        // drains V(t) only (K now reg-staged) — issued ~2000cyc ago
    BARRIER();  // B3: P/resc/gflag + K-writes + V(t) all certified
    gf = gflag[cur];
  }

  doPV(gf);  // final PV (V(NT-1) certified at last B3)

  // epilogue: O / l
#pragma unroll
  for (int mf = 0; mf < 4; ++mf) {
#pragma unroll
    for (int r = 0; r < 4; ++r) {
      int row = mf * 16 + lg * 4 + r;
      float inv = 1.0f / lstate[row];
      float* op = Out + ((size_t)b * SREF + q0 + row) * 512 + wid * 64;
#pragma unroll
      for (int nf = 0; nf < 4; ++nf) op[nf * 16 + lr] = oacc[mf][nf][r] * inv;
    }
  }
}

extern "C" void kernel_launch(void* const* d_in, const int* in_sizes, int n_in,
                              void* d_out, int out_size, void* d_ws, size_t ws_size,
                              hipStream_t stream) {
  const float* X  = (const float*)d_in[0];
  const float* Wq = (const float*)d_in[1];
  const float* bq = (const float*)d_in[2];
  const float* Wk = (const float*)d_in[3];
  const float* bk = (const float*)d_in[4];
  const float* Wv = (const float*)d_in[5];
  const float* bv = (const float*)d_in[6];
  ushort* ws = (ushort*)d_ws;
  float* out = (float*)d_out;

  // d_out doubles as scratch for bf16 W^T until attn overwrites it.
  ushort* Wt = (ushort*)d_out;

  wprep_kernel<<<dim3(192), dim3(256), 0, stream>>>(Wq, Wk, Wv, Wt);

  dim3 g1(M_ / 64, D_ / 64), b1(256);
  qkv_kernel<<<g1, b1, 0, stream>>>(X, Wt, bq, bk, bv, ws);

  attn_kernel<<<dim3(SREF / QT, 8), dim3(512), 0, stream>>>(
      ws, ws + (size_t)M_ * D_, ws + 2 * (size_t)M_ * D_, out);
}

// Round 14
// 174.813 us; speedup vs baseline: 2.1207x; 2.1207x over previous
//
#include <hip/hip_runtime.h>
#include <hip/hip_bf16.h>
#include <stdint.h>

typedef __attribute__((ext_vector_type(8))) short short8;
typedef __attribute__((ext_vector_type(4))) float f32x4;

#define MFMA16(a, b, c) __builtin_amdgcn_mfma_f32_16x16x32_bf16(a, b, c, 0, 0, 0)

#define D_ 512
#define M_ 16384
#define SREF 2048
#define QT 64
#define KT 64
#define NT (SREF / KT)

#define VM0  asm volatile("s_waitcnt vmcnt(0)" ::: "memory")
#define LGKM0 asm volatile("s_waitcnt lgkmcnt(0)" ::: "memory")
#define BARRIER() do { asm volatile("s_waitcnt lgkmcnt(0)" ::: "memory"); \
                       __builtin_amdgcn_s_barrier(); \
                       asm volatile("" ::: "memory"); } while (0)

__device__ __forceinline__ ushort f2bf(float f) {
  union { float f; uint32_t u; } v; v.f = f;
  uint32_t r = v.u + 0x7fffu + ((v.u >> 16) & 1u);
  return (ushort)(r >> 16);
}

__device__ __forceinline__ void gld16(const void* g, void* l) {
  __builtin_amdgcn_global_load_lds(
      (const __attribute__((address_space(1))) void*)g,
      (__attribute__((address_space(3))) void*)l, 16, 0, 0);
}

// DPP cross-lane (VALU pipe): xor1 = quad_perm 0xB1, xor2 = 0x4E.
__device__ __forceinline__ float dppmax1(float v) {
  int x = __builtin_amdgcn_mov_dpp(__float_as_int(v), 0xB1, 0xF, 0xF, true);
  return fmaxf(v, __int_as_float(x));
}
__device__ __forceinline__ float dppmax2(float v) {
  int x = __builtin_amdgcn_mov_dpp(__float_as_int(v), 0x4E, 0xF, 0xF, true);
  return fmaxf(v, __int_as_float(x));
}
__device__ __forceinline__ float dppadd1(float v) {
  int x = __builtin_amdgcn_mov_dpp(__float_as_int(v), 0xB1, 0xF, 0xF, true);
  return v + __int_as_float(x);
}
__device__ __forceinline__ float dppadd2(float v) {
  int x = __builtin_amdgcn_mov_dpp(__float_as_int(v), 0x4E, 0xF, 0xF, true);
  return v + __int_as_float(x);
}

// ---------------- K0: fused prep (X->bf16, W->bf16 W^T) ------------------
__global__ __launch_bounds__(256) void prep_kernel(
    const float* __restrict__ X,
    const float* __restrict__ Wq, const float* __restrict__ Wk,
    const float* __restrict__ Wv, ushort* __restrict__ Xb,
    ushort* __restrict__ Wt) {
  const int bid = blockIdx.x;
  if (bid < 4096) {
    size_t i = ((size_t)bid * 256 + threadIdx.x) * 8;
    float4 a = *(const float4*)(X + i);
    float4 c = *(const float4*)(X + i + 4);
    union { ushort u[8]; short8 v; } r;
    r.u[0] = f2bf(a.x); r.u[1] = f2bf(a.y); r.u[2] = f2bf(a.z); r.u[3] = f2bf(a.w);
    r.u[4] = f2bf(c.x); r.u[5] = f2bf(c.y); r.u[6] = f2bf(c.z); r.u[7] = f2bf(c.w);
    *(short8*)(Xb + i) = r.v;
    return;
  }
  const int wb = bid - 4096;
  const int z = wb >> 6;
  const int k0 = ((wb >> 3) & 7) * 64, n0 = (wb & 7) * 64;
  const float* W = (z == 0) ? Wq : ((z == 1) ? Wk : Wv);
  ushort* dst = Wt + (size_t)z * D_ * D_;
  __shared__ ushort T[64][72];
  const int r = threadIdx.x >> 3, c = (threadIdx.x & 7) * 8;
#pragma unroll
  for (int p = 0; p < 2; ++p) {
    int rr = p * 32 + r;
    const float* src = W + (size_t)(k0 + rr) * D_ + n0 + c;
    float4 a = *(const float4*)src;
    float4 b = *(const float4*)(src + 4);
    T[c + 0][rr] = f2bf(a.x); T[c + 1][rr] = f2bf(a.y);
    T[c + 2][rr] = f2bf(a.z); T[c + 3][rr] = f2bf(a.w);
    T[c + 4][rr] = f2bf(b.x); T[c + 5][rr] = f2bf(b.y);
    T[c + 6][rr] = f2bf(b.z); T[c + 7][rr] = f2bf(b.w);
  }
  __syncthreads();
#pragma unroll
  for (int p = 0; p < 2; ++p) {
    int rr = p * 32 + r;
    *(short8*)(dst + (size_t)(n0 + rr) * D_ + k0 + c) = *(const short8*)&T[rr][c];
  }
}

// ---------------- K1: fused QKV projection (3 GEMMs, one X pass) ---------
// z=0: Q pre-scaled by log2e/sqrt(512) (softmax runs in exp2 domain);
// z=1: K row-major; z=2: V^T [b][d][s]
__global__ __launch_bounds__(256) void qkv_kernel(
    const ushort* __restrict__ Xb, const ushort* __restrict__ Wt,
    const float* __restrict__ bq, const float* __restrict__ bk,
    const float* __restrict__ bv, ushort* __restrict__ ws) {
  const int m0 = blockIdx.x * 64;
  const int n0 = blockIdx.y * 64;
  const int tid = threadIdx.x;
  const int lane = tid & 63;
  const int wid = tid >> 6;
  const int lr = lane & 15;
  const int lg = lane >> 4;
  const int m_base = (wid >> 1) * 32;
  const int n_base = (wid & 1) * 32;

  __shared__ union {
    struct { ushort At[64][32]; ushort Bt[3][64][32]; } s;
    ushort bounce[64][72];
  } u;

  f32x4 acc[3][2][2] = {};
  const int l4r = lane >> 2, l4c = (lane & 3) * 8;

  for (int ks = 0; ks < 16; ++ks) {
    const int k0 = ks * 32;
    gld16(Xb + (size_t)(m0 + wid * 16 + l4r) * D_ + k0 + l4c, &u.s.At[wid * 16][0]);
#pragma unroll
    for (int z = 0; z < 3; ++z)
      gld16(Wt + (size_t)z * D_ * D_ + (size_t)(n0 + wid * 16 + l4r) * D_ + k0 + l4c,
            &u.s.Bt[z][wid * 16][0]);
    __syncthreads();
    short8 a[2];
#pragma unroll
    for (int mf = 0; mf < 2; ++mf)
      a[mf] = *(const short8*)&u.s.At[m_base + mf * 16 + lr][lg * 8];
#pragma unroll
    for (int z = 0; z < 3; ++z) {
#pragma unroll
      for (int nf = 0; nf < 2; ++nf) {
        short8 b = *(const short8*)&u.s.Bt[z][n_base + nf * 16 + lr][lg * 8];
#pragma unroll
        for (int mf = 0; mf < 2; ++mf)
          acc[z][mf][nf] = MFMA16(a[mf], b, acc[z][mf][nf]);
      }
    }
    __syncthreads();
  }

  const int b_idx = m0 >> 11;
  const int s0 = m0 & 2047;
  const float qscale = 0.06377576f;  // log2(e)/sqrt(512): exp2-domain softmax
#pragma unroll
  for (int z = 0; z < 2; ++z) {
    const float* bias = (z == 0) ? bq : bk;
    ushort* outp = ws + (size_t)z * M_ * D_;
#pragma unroll
    for (int mf = 0; mf < 2; ++mf) {
#pragma unroll
      for (int nf = 0; nf < 2; ++nf) {
        int n = n0 + n_base + nf * 16 + lr;
        float bvv = bias[n];
        int mrow = m_base + mf * 16 + lg * 4;
#pragma unroll
        for (int r = 0; r < 4; ++r) {
          float v = acc[z][mf][nf][r] + bvv;
          if (z == 0) v *= qscale;
          outp[(size_t)(m0 + mrow + r) * D_ + n] = f2bf(v);
        }
      }
    }
  }
#pragma unroll
  for (int mf = 0; mf < 2; ++mf) {
#pragma unroll
    for (int nf = 0; nf < 2; ++nf) {
      int nloc = n_base + nf * 16 + lr;
      float bvv = bv[n0 + nloc];
      int mrow = m_base + mf * 16 + lg * 4;
      ushort4 st;
      st.x = f2bf(acc[2][mf][nf][0] + bvv);
      st.y = f2bf(acc[2][mf][nf][1] + bvv);
      st.z = f2bf(acc[2][mf][nf][2] + bvv);
      st.w = f2bf(acc[2][mf][nf][3] + bvv);
      *(ushort4*)&u.bounce[nloc][mrow] = st;
    }
  }
  __syncthreads();
  ushort* vout = ws + 2 * (size_t)M_ * D_;
  const int rr = tid >> 3, cc = (tid & 7) * 8;
#pragma unroll
  for (int p = 0; p < 2; ++p) {
    int d = p * 32 + rr;
    *(short8*)(vout + ((size_t)b_idx * 512 + n0 + d) * 2048 + s0 + cc) =
        *(const short8*)&u.bounce[d][cc];
  }
}

// ---------------- K2: flash attention, KT=64, single-buffer K/V ----------
// r12 structure (best measured: attn 133.4us). Softmax in exp2 domain
// (Q pre-scaled by log2e/sqrt(512); defer threshold 11.5 = 8*log2e).
// Register wall (hard, measured r6/r11/r13): qf(64)+oacc(64 AGPR) fills
// the 256-reg unified budget at 2 waves/SIMD — any +32-reg scheme spills,
// (512,4) spills, qf[2][16] spills. Do not re-attempt.
__global__ __launch_bounds__(512, 2) void attn_kernel(
    const ushort* __restrict__ Qg, const ushort* __restrict__ Kg,
    const ushort* __restrict__ Vtg, float* __restrict__ Out) {
  const int b = blockIdx.y;
  const int q0 = blockIdx.x * QT;
  const int tid = threadIdx.x;
  const int lane = tid & 63;
  const int wid = tid >> 6;
  const int lr = lane & 15;
  const int lg = lane >> 4;
  const int mw = wid >> 1;   // 0..3  q-16-chunk (QK^T)
  const int nw = wid & 1;    // 0..1  kv-32-chunk (QK^T, 2 n-frags each)

  __shared__ __align__(16) ushort Ks[KT * 512];   // 64 KB, K rows XOR-swz
  __shared__ __align__(16) ushort Vs[512 * KT];   // 64 KB, V^T rows slot-swz
  __shared__ __align__(16) char  SsF[64 * 256];   // 16 KB, S f32, slot XOR row&7
  __shared__ __align__(16) char  PsB[64 * 128];   // 8 KB, P bf16, slot XOR row&7
  __shared__ float mstate[QT], lstate[QT], resc[QT];
  __shared__ int gflag[2];

  const ushort* Qrow = Qg + ((size_t)b * SREF + q0) * 512;
  const ushort* Krow = Kg + (size_t)b * SREF * 512;
  const ushort* Vrow = Vtg + (size_t)b * 512 * 2048;

  // Q A-frags: wave's 16 q-rows x D=512: 64 VGPRs
  short8 qf[16];
  {
    const ushort* qp = Qrow + (size_t)(mw * 16 + lr) * 512 + lg * 8;
#pragma unroll
    for (int ks = 0; ks < 16; ++ks) qf[ks] = *(const short8*)(qp + ks * 32);
  }
  if (tid < QT) { mstate[tid] = -1e30f; lstate[tid] = 0.0f; }

  f32x4 oacc[4][4] = {};

  auto issueK = [&](int t) {
#pragma unroll
    for (int ii = 0; ii < 8; ++ii) {
      int r = wid * 8 + ii;
      gld16(Krow + (size_t)(t * KT + r) * 512 + ((lane ^ (r & 7)) * 8), &Ks[r * 512]);
    }
  };
  auto issueV = [&](int t) {
#pragma unroll
    for (int ii = 0; ii < 8; ++ii) {
      int i = wid * 8 + ii;              // 8 d-rows per instr; wave owns d-chunk
      int rloc = lane >> 3;              // 0..7
      int d = i * 8 + rloc;              // d&7 == rloc
      int cs = (lane & 7) ^ rloc;        // pre-swizzled col slot (16B units)
      gld16(Vrow + (size_t)d * 2048 + t * KT + cs * 8, &Vs[i * 512]);
    }
  };
  auto doPV = [&](int gf) {
    if (gf) {
#pragma unroll
      for (int mf = 0; mf < 4; ++mf) {
        f32x4 rv;
#pragma unroll
        for (int r = 0; r < 4; ++r) rv[r] = resc[mf * 16 + lg * 4 + r];
#pragma unroll
        for (int nf = 0; nf < 4; ++nf) oacc[mf][nf] *= rv;
      }
    }
#pragma unroll
    for (int kk = 0; kk < 2; ++kk) {
      short8 pA[4];
#pragma unroll
      for (int mf = 0; mf < 4; ++mf) {
        int row = mf * 16 + lr;
        pA[mf] = *(const short8*)(PsB + row * 128 + (((kk * 4 + lg) ^ (row & 7)) << 4));
      }
      __builtin_amdgcn_s_setprio(1);
#pragma unroll
      for (int nf = 0; nf < 4; ++nf) {
        int d = wid * 64 + nf * 16 + lr;
        short8 vB = *(const short8*)((const char*)Vs + d * 128 +
                                     (((kk * 4 + lg) ^ (d & 7)) << 4));
#pragma unroll
        for (int mf = 0; mf < 4; ++mf) oacc[mf][nf] = MFMA16(pA[mf], vB, oacc[mf][nf]);
      }
      __builtin_amdgcn_s_setprio(0);
    }
  };

  issueK(0);
  VM0;        // prologue: K(0) landed
  BARRIER();  // all waves' K(0) staged + state init visible
  int gf = 0;

  for (int t = 0; t < NT; ++t) {
    const int cur = t & 1;
    // ---- window A: PV(t-1) | V(t) issue | QK^T(t) ----
    if (t > 0) {
      doPV(gf);   // reads Vs=V(t-1), PsB=P(t-1) — certified at B3(t-1)
      LGKM0;      // own V-row reads done before re-staging them
    }
    issueV(t);
    __builtin_amdgcn_sched_barrier(0);  // pin V-issue before QK^T (cover)
    if (tid == 0) gflag[cur] = 0;
    {
      // QK^T: wave's 16 q-rows x 64 kv (2 n-frags); Q reused from regs
      f32x4 s0v = {0.f, 0.f, 0.f, 0.f}, s1v = {0.f, 0.f, 0.f, 0.f};
      const int krow = nw * 32 + lr;
      const char* kb0 = (const char*)Ks + krow * 1024;
      const char* kb1 = kb0 + 16 * 1024;   // krow+16: same XOR (16 = 0 mod 8)
      const int kx = (krow & 7) << 4;
      __builtin_amdgcn_s_setprio(1);
#pragma unroll
      for (int ks = 0; ks < 16; ++ks) {
        int off = (ks * 64 + lg * 16) ^ kx;
        short8 b0 = *(const short8*)(kb0 + off);
        short8 b1 = *(const short8*)(kb1 + off);
        s0v = MFMA16(qf[ks], b0, s0v);
        s1v = MFMA16(qf[ks], b1, s1v);
      }
      __builtin_amdgcn_s_setprio(0);
#pragma unroll
      for (int nf2 = 0; nf2 < 2; ++nf2) {
        f32x4 sv = (nf2 == 0) ? s0v : s1v;
        int c = nw * 32 + nf2 * 16 + lr;
#pragma unroll
        for (int r = 0; r < 4; ++r) {
          int row = mw * 16 + lg * 4 + r;
          *(float*)(SsF + row * 256 + ((((c >> 2) ^ (row & 7)) << 4) | ((c & 3) << 2))) = sv[r];
        }
      }
    }
    BARRIER();  // B2: S visible; Ks reads done; PsB reads (doPV) done

    // ---- window B: K(t+1) restage + softmax (defer-max, exp2 domain) ----
    if (t + 1 < NT) issueK(t + 1);   // Ks reads completed at B2
    __builtin_amdgcn_sched_barrier(0);  // pin K-issue before softmax (cover)
    {
      int row = tid >> 3, ic = tid & 7;
      float4 sa = *(const float4*)(SsF + row * 256 + ((((ic * 2) ^ (row & 7)) << 4)));
      float4 sb = *(const float4*)(SsF + row * 256 + ((((ic * 2 + 1) ^ (row & 7)) << 4)));
      float mx = fmaxf(fmaxf(fmaxf(sa.x, sa.y), fmaxf(sa.z, sa.w)),
                       fmaxf(fmaxf(sb.x, sb.y), fmaxf(sb.z, sb.w)));
      mx = dppmax1(mx); mx = dppmax2(mx); mx = fmaxf(mx, __shfl_xor(mx, 4));
      float mold = mstate[row];
      bool grow = (mx > mold + 11.5f);   // 8*log2e in exp2 domain
      float mref = grow ? mx : mold;
      float p0 = exp2f(sa.x - mref), p1 = exp2f(sa.y - mref);
      float p2 = exp2f(sa.z - mref), p3 = exp2f(sa.w - mref);
      float p4 = exp2f(sb.x - mref), p5 = exp2f(sb.y - mref);
      float p6 = exp2f(sb.z - mref), p7 = exp2f(sb.w - mref);
      float psum = ((p0 + p1) + (p2 + p3)) + ((p4 + p5) + (p6 + p7));
      psum = dppadd1(psum); psum = dppadd2(psum); psum += __shfl_xor(psum, 4);
      union { ushort u[8]; short8 v; } pb;
      pb.u[0] = f2bf(p0); pb.u[1] = f2bf(p1); pb.u[2] = f2bf(p2); pb.u[3] = f2bf(p3);
      pb.u[4] = f2bf(p4); pb.u[5] = f2bf(p5); pb.u[6] = f2bf(p6); pb.u[7] = f2bf(p7);
      *(short8*)(PsB + row * 128 + ((ic ^ (row & 7)) << 4)) = pb.v;
      if (ic == 0) {
        float sc = grow ? exp2f(mold - mx) : 1.0f;
        resc[row] = sc;
        lstate[row] = lstate[row] * sc + psum;
        if (grow) { mstate[row] = mx; gflag[cur] = 1; }
      }
    }
    VM0;        // V(t) + K(t+1) certified landed (cross-wave safe after B3)
    BARRIER();  // B3: P/resc/gflag visible + staged tiles certified
    gf = gflag[cur];
  }

  doPV(gf);  // final PV (V(NT-1) certified at last B3)

  // epilogue: O / l
#pragma unroll
  for (int mf = 0; mf < 4; ++mf) {
#pragma unroll
    for (int r = 0; r < 4; ++r) {
      int row = mf * 16 + lg * 4 + r;
      float inv = 1.0f / lstate[row];
      float* op = Out + ((size_t)b * SREF + q0 + row) * 512 + wid * 64;
#pragma unroll
      for (int nf = 0; nf < 4; ++nf) op[nf * 16 + lr] = oacc[mf][nf][r] * inv;
    }
  }
}

extern "C" void kernel_launch(void* const* d_in, const int* in_sizes, int n_in,
                              void* d_out, int out_size, void* d_ws, size_t ws_size,
                              hipStream_t stream) {
  const float* X  = (const float*)d_in[0];
  const float* Wq = (const float*)d_in[1];
  const float* bq = (const float*)d_in[2];
  const float* Wk = (const float*)d_in[3];
  const float* bk = (const float*)d_in[4];
  const float* Wv = (const float*)d_in[5];
  const float* bv = (const float*)d_in[6];
  ushort* ws = (ushort*)d_ws;
  float* out = (float*)d_out;

  // d_out doubles as scratch for bf16 X and W^T until attn overwrites it.
  ushort* Xb = (ushort*)d_out;
  ushort* Wt = Xb + (size_t)M_ * D_;

  prep_kernel<<<dim3(4096 + 192), dim3(256), 0, stream>>>(X, Wq, Wk, Wv, Xb, Wt);

  dim3 g1(M_ / 64, D_ / 64), b1(256);
  qkv_kernel<<<g1, b1, 0, stream>>>(Xb, Wt, bq, bk, bv, ws);

  attn_kernel<<<dim3(SREF / QT, 8), dim3(512), 0, stream>>>(
      ws, ws + (size_t)M_ * D_, ws + 2 * (size_t)M_ * D_, out);
}

// Round 15
// 172.411 us; speedup vs baseline: 2.1503x; 1.0139x over previous
//
#include <hip/hip_runtime.h>
#include <hip/hip_bf16.h>
#include <stdint.h>

typedef __attribute__((ext_vector_type(8))) short short8;
typedef __attribute__((ext_vector_type(4))) float f32x4;

#define MFMA16(a, b, c) __builtin_amdgcn_mfma_f32_16x16x32_bf16(a, b, c, 0, 0, 0)

#define D_ 512
#define M_ 16384
#define SREF 2048
#define QT 64
#define KT 64
#define NT (SREF / KT)

#define VM0  asm volatile("s_waitcnt vmcnt(0)" ::: "memory")
#define LGKM0 asm volatile("s_waitcnt lgkmcnt(0)" ::: "memory")
#define BARRIER() do { asm volatile("s_waitcnt lgkmcnt(0)" ::: "memory"); \
                       __builtin_amdgcn_s_barrier(); \
                       asm volatile("" ::: "memory"); } while (0)

__device__ __forceinline__ ushort f2bf(float f) {
  union { float f; uint32_t u; } v; v.f = f;
  uint32_t r = v.u + 0x7fffu + ((v.u >> 16) & 1u);
  return (ushort)(r >> 16);
}

__device__ __forceinline__ void gld16(const void* g, void* l) {
  __builtin_amdgcn_global_load_lds(
      (const __attribute__((address_space(1))) void*)g,
      (__attribute__((address_space(3))) void*)l, 16, 0, 0);
}

// DPP cross-lane (VALU pipe): xor1 = quad_perm 0xB1, xor2 = 0x4E.
__device__ __forceinline__ float dppmax1(float v) {
  int x = __builtin_amdgcn_mov_dpp(__float_as_int(v), 0xB1, 0xF, 0xF, true);
  return fmaxf(v, __int_as_float(x));
}
__device__ __forceinline__ float dppmax2(float v) {
  int x = __builtin_amdgcn_mov_dpp(__float_as_int(v), 0x4E, 0xF, 0xF, true);
  return fmaxf(v, __int_as_float(x));
}
__device__ __forceinline__ float dppadd1(float v) {
  int x = __builtin_amdgcn_mov_dpp(__float_as_int(v), 0xB1, 0xF, 0xF, true);
  return v + __int_as_float(x);
}
__device__ __forceinline__ float dppadd2(float v) {
  int x = __builtin_amdgcn_mov_dpp(__float_as_int(v), 0x4E, 0xF, 0xF, true);
  return v + __int_as_float(x);
}

// ---------------- K0: fused prep (X->bf16, W->bf16 W^T) ------------------
__global__ __launch_bounds__(256) void prep_kernel(
    const float* __restrict__ X,
    const float* __restrict__ Wq, const float* __restrict__ Wk,
    const float* __restrict__ Wv, ushort* __restrict__ Xb,
    ushort* __restrict__ Wt) {
  const int bid = blockIdx.x;
  if (bid < 4096) {
    size_t i = ((size_t)bid * 256 + threadIdx.x) * 8;
    float4 a = *(const float4*)(X + i);
    float4 c = *(const float4*)(X + i + 4);
    union { ushort u[8]; short8 v; } r;
    r.u[0] = f2bf(a.x); r.u[1] = f2bf(a.y); r.u[2] = f2bf(a.z); r.u[3] = f2bf(a.w);
    r.u[4] = f2bf(c.x); r.u[5] = f2bf(c.y); r.u[6] = f2bf(c.z); r.u[7] = f2bf(c.w);
    *(short8*)(Xb + i) = r.v;
    return;
  }
  const int wb = bid - 4096;
  const int z = wb >> 6;
  const int k0 = ((wb >> 3) & 7) * 64, n0 = (wb & 7) * 64;
  const float* W = (z == 0) ? Wq : ((z == 1) ? Wk : Wv);
  ushort* dst = Wt + (size_t)z * D_ * D_;
  __shared__ ushort T[64][72];
  const int r = threadIdx.x >> 3, c = (threadIdx.x & 7) * 8;
#pragma unroll
  for (int p = 0; p < 2; ++p) {
    int rr = p * 32 + r;
    const float* src = W + (size_t)(k0 + rr) * D_ + n0 + c;
    float4 a = *(const float4*)src;
    float4 b = *(const float4*)(src + 4);
    T[c + 0][rr] = f2bf(a.x); T[c + 1][rr] = f2bf(a.y);
    T[c + 2][rr] = f2bf(a.z); T[c + 3][rr] = f2bf(a.w);
    T[c + 4][rr] = f2bf(b.x); T[c + 5][rr] = f2bf(b.y);
    T[c + 6][rr] = f2bf(b.z); T[c + 7][rr] = f2bf(b.w);
  }
  __syncthreads();
#pragma unroll
  for (int p = 0; p < 2; ++p) {
    int rr = p * 32 + r;
    *(short8*)(dst + (size_t)(n0 + rr) * D_ + k0 + c) = *(const short8*)&T[rr][c];
  }
}

// ---------------- K1: fused QKV projection (3 GEMMs, one X pass) ---------
// z=0: Q (pre-scaled by 1/sqrt(512)), z=1: K row-major; z=2: V^T [b][d][s]
__global__ __launch_bounds__(256) void qkv_kernel(
    const ushort* __restrict__ Xb, const ushort* __restrict__ Wt,
    const float* __restrict__ bq, const float* __restrict__ bk,
    const float* __restrict__ bv, ushort* __restrict__ ws) {
  const int m0 = blockIdx.x * 64;
  const int n0 = blockIdx.y * 64;
  const int tid = threadIdx.x;
  const int lane = tid & 63;
  const int wid = tid >> 6;
  const int lr = lane & 15;
  const int lg = lane >> 4;
  const int m_base = (wid >> 1) * 32;
  const int n_base = (wid & 1) * 32;

  __shared__ union {
    struct { ushort At[64][32]; ushort Bt[3][64][32]; } s;
    ushort bounce[64][72];
  } u;

  f32x4 acc[3][2][2] = {};
  const int l4r = lane >> 2, l4c = (lane & 3) * 8;

  for (int ks = 0; ks < 16; ++ks) {
    const int k0 = ks * 32;
    gld16(Xb + (size_t)(m0 + wid * 16 + l4r) * D_ + k0 + l4c, &u.s.At[wid * 16][0]);
#pragma unroll
    for (int z = 0; z < 3; ++z)
      gld16(Wt + (size_t)z * D_ * D_ + (size_t)(n0 + wid * 16 + l4r) * D_ + k0 + l4c,
            &u.s.Bt[z][wid * 16][0]);
    __syncthreads();
    short8 a[2];
#pragma unroll
    for (int mf = 0; mf < 2; ++mf)
      a[mf] = *(const short8*)&u.s.At[m_base + mf * 16 + lr][lg * 8];
#pragma unroll
    for (int z = 0; z < 3; ++z) {
#pragma unroll
      for (int nf = 0; nf < 2; ++nf) {
        short8 b = *(const short8*)&u.s.Bt[z][n_base + nf * 16 + lr][lg * 8];
#pragma unroll
        for (int mf = 0; mf < 2; ++mf)
          acc[z][mf][nf] = MFMA16(a[mf], b, acc[z][mf][nf]);
      }
    }
    __syncthreads();
  }

  const int b_idx = m0 >> 11;
  const int s0 = m0 & 2047;
  const float qscale = 0.04419417382415922f;  // 1/sqrt(512)
#pragma unroll
  for (int z = 0; z < 2; ++z) {
    const float* bias = (z == 0) ? bq : bk;
    ushort* outp = ws + (size_t)z * M_ * D_;
#pragma unroll
    for (int mf = 0; mf < 2; ++mf) {
#pragma unroll
      for (int nf = 0; nf < 2; ++nf) {
        int n = n0 + n_base + nf * 16 + lr;
        float bvv = bias[n];
        int mrow = m_base + mf * 16 + lg * 4;
#pragma unroll
        for (int r = 0; r < 4; ++r) {
          float v = acc[z][mf][nf][r] + bvv;
          if (z == 0) v *= qscale;
          outp[(size_t)(m0 + mrow + r) * D_ + n] = f2bf(v);
        }
      }
    }
  }
#pragma unroll
  for (int mf = 0; mf < 2; ++mf) {
#pragma unroll
    for (int nf = 0; nf < 2; ++nf) {
      int nloc = n_base + nf * 16 + lr;
      float bvv = bv[n0 + nloc];
      int mrow = m_base + mf * 16 + lg * 4;
      ushort4 st;
      st.x = f2bf(acc[2][mf][nf][0] + bvv);
      st.y = f2bf(acc[2][mf][nf][1] + bvv);
      st.z = f2bf(acc[2][mf][nf][2] + bvv);
      st.w = f2bf(acc[2][mf][nf][3] + bvv);
      *(ushort4*)&u.bounce[nloc][mrow] = st;
    }
  }
  __syncthreads();
  ushort* vout = ws + 2 * (size_t)M_ * D_;
  const int rr = tid >> 3, cc = (tid & 7) * 8;
#pragma unroll
  for (int p = 0; p < 2; ++p) {
    int d = p * 32 + rr;
    *(short8*)(vout + ((size_t)b_idx * 512 + n0 + d) * 2048 + s0 + cc) =
        *(const short8*)&u.bounce[d][cc];
  }
}

// ---------------- K2: flash attention, KT=64, single-buffer K/V ----------
// r12 configuration — measured best (attn 133.4us, total 172.5us).
// Structural doors measured-closed: (512,4) spills (r6); qf[2][16] K-reuse
// spills (r11); +32-reg K-stage spills (r13); V/K-in-regs scattered loads
// lose to DMA+LDS (r5/r8); in-reg softmax needs 128-AGPR oacc at D=512;
// 32x32 QK^T forces Q out of regs; bank-conflict counter is DMA-write
// accounting (exactly 1024/tile/CU), not fixable conflicts.
__global__ __launch_bounds__(512, 2) void attn_kernel(
    const ushort* __restrict__ Qg, const ushort* __restrict__ Kg,
    const ushort* __restrict__ Vtg, float* __restrict__ Out) {
  const int b = blockIdx.y;
  const int q0 = blockIdx.x * QT;
  const int tid = threadIdx.x;
  const int lane = tid & 63;
  const int wid = tid >> 6;
  const int lr = lane & 15;
  const int lg = lane >> 4;
  const int mw = wid >> 1;   // 0..3  q-16-chunk (QK^T)
  const int nw = wid & 1;    // 0..1  kv-32-chunk (QK^T, 2 n-frags each)

  __shared__ __align__(16) ushort Ks[KT * 512];   // 64 KB, K rows XOR-swz
  __shared__ __align__(16) ushort Vs[512 * KT];   // 64 KB, V^T rows slot-swz
  __shared__ __align__(16) char  SsF[64 * 256];   // 16 KB, S f32, slot XOR row&7
  __shared__ __align__(16) char  PsB[64 * 128];   // 8 KB, P bf16, slot XOR row&7
  __shared__ float mstate[QT], lstate[QT], resc[QT];
  __shared__ int gflag[2];

  const ushort* Qrow = Qg + ((size_t)b * SREF + q0) * 512;
  const ushort* Krow = Kg + (size_t)b * SREF * 512;
  const ushort* Vrow = Vtg + (size_t)b * 512 * 2048;

  // Q A-frags: wave's 16 q-rows x D=512: 64 VGPRs
  short8 qf[16];
  {
    const ushort* qp = Qrow + (size_t)(mw * 16 + lr) * 512 + lg * 8;
#pragma unroll
    for (int ks = 0; ks < 16; ++ks) qf[ks] = *(const short8*)(qp + ks * 32);
  }
  if (tid < QT) { mstate[tid] = -1e30f; lstate[tid] = 0.0f; }

  f32x4 oacc[4][4] = {};

  auto issueK = [&](int t) {
#pragma unroll
    for (int ii = 0; ii < 8; ++ii) {
      int r = wid * 8 + ii;
      gld16(Krow + (size_t)(t * KT + r) * 512 + ((lane ^ (r & 7)) * 8), &Ks[r * 512]);
    }
  };
  auto issueV = [&](int t) {
#pragma unroll
    for (int ii = 0; ii < 8; ++ii) {
      int i = wid * 8 + ii;              // 8 d-rows per instr; wave owns d-chunk
      int rloc = lane >> 3;              // 0..7
      int d = i * 8 + rloc;              // d&7 == rloc
      int cs = (lane & 7) ^ rloc;        // pre-swizzled col slot (16B units)
      gld16(Vrow + (size_t)d * 2048 + t * KT + cs * 8, &Vs[i * 512]);
    }
  };
  auto doPV = [&](int gf) {
    if (gf) {
#pragma unroll
      for (int mf = 0; mf < 4; ++mf) {
        f32x4 rv;
#pragma unroll
        for (int r = 0; r < 4; ++r) rv[r] = resc[mf * 16 + lg * 4 + r];
#pragma unroll
        for (int nf = 0; nf < 4; ++nf) oacc[mf][nf] *= rv;
      }
    }
#pragma unroll
    for (int kk = 0; kk < 2; ++kk) {
      short8 pA[4];
#pragma unroll
      for (int mf = 0; mf < 4; ++mf) {
        int row = mf * 16 + lr;
        pA[mf] = *(const short8*)(PsB + row * 128 + (((kk * 4 + lg) ^ (row & 7)) << 4));
      }
      __builtin_amdgcn_s_setprio(1);
#pragma unroll
      for (int nf = 0; nf < 4; ++nf) {
        int d = wid * 64 + nf * 16 + lr;
        short8 vB = *(const short8*)((const char*)Vs + d * 128 +
                                     (((kk * 4 + lg) ^ (d & 7)) << 4));
#pragma unroll
        for (int mf = 0; mf < 4; ++mf) oacc[mf][nf] = MFMA16(pA[mf], vB, oacc[mf][nf]);
      }
      __builtin_amdgcn_s_setprio(0);
    }
  };

  issueK(0);
  VM0;        // prologue: K(0) landed
  BARRIER();  // all waves' K(0) staged + state init visible
  int gf = 0;

  for (int t = 0; t < NT; ++t) {
    const int cur = t & 1;
    // ---- window A: PV(t-1) | V(t) issue | QK^T(t) ----
    if (t > 0) {
      doPV(gf);   // reads Vs=V(t-1), PsB=P(t-1) — certified at B3(t-1)
      LGKM0;      // own V-row reads done before re-staging them
    }
    issueV(t);
    if (tid == 0) gflag[cur] = 0;
    {
      // QK^T: wave's 16 q-rows x 64 kv (2 n-frags); Q reused from regs
      f32x4 s0v = {0.f, 0.f, 0.f, 0.f}, s1v = {0.f, 0.f, 0.f, 0.f};
      const int krow = nw * 32 + lr;
      const char* kb0 = (const char*)Ks + krow * 1024;
      const char* kb1 = kb0 + 16 * 1024;   // krow+16: same XOR (16 = 0 mod 8)
      const int kx = (krow & 7) << 4;
      __builtin_amdgcn_s_setprio(1);
#pragma unroll
      for (int ks = 0; ks < 16; ++ks) {
        int off = (ks * 64 + lg * 16) ^ kx;
        short8 b0 = *(const short8*)(kb0 + off);
        short8 b1 = *(const short8*)(kb1 + off);
        s0v = MFMA16(qf[ks], b0, s0v);
        s1v = MFMA16(qf[ks], b1, s1v);
      }
      __builtin_amdgcn_s_setprio(0);
#pragma unroll
      for (int nf2 = 0; nf2 < 2; ++nf2) {
        f32x4 sv = (nf2 == 0) ? s0v : s1v;
        int c = nw * 32 + nf2 * 16 + lr;
#pragma unroll
        for (int r = 0; r < 4; ++r) {
          int row = mw * 16 + lg * 4 + r;
          *(float*)(SsF + row * 256 + ((((c >> 2) ^ (row & 7)) << 4) | ((c & 3) << 2))) = sv[r];
        }
      }
    }
    BARRIER();  // B2: S visible; Ks reads done; PsB reads (doPV) done

    // ---- window B: K(t+1) restage + softmax (defer-max THR=8) ----
    if (t + 1 < NT) issueK(t + 1);   // Ks reads completed at B2
    {
      int row = tid >> 3, ic = tid & 7;
      float4 sa = *(const float4*)(SsF + row * 256 + ((((ic * 2) ^ (row & 7)) << 4)));
      float4 sb = *(const float4*)(SsF + row * 256 + ((((ic * 2 + 1) ^ (row & 7)) << 4)));
      float mx = fmaxf(fmaxf(fmaxf(sa.x, sa.y), fmaxf(sa.z, sa.w)),
                       fmaxf(fmaxf(sb.x, sb.y), fmaxf(sb.z, sb.w)));
      mx = dppmax1(mx); mx = dppmax2(mx); mx = fmaxf(mx, __shfl_xor(mx, 4));
      float mold = mstate[row];
      bool grow = (mx > mold + 8.0f);
      float mref = grow ? mx : mold;
      float p0 = __expf(sa.x - mref), p1 = __expf(sa.y - mref);
      float p2 = __expf(sa.z - mref), p3 = __expf(sa.w - mref);
      float p4 = __expf(sb.x - mref), p5 = __expf(sb.y - mref);
      float p6 = __expf(sb.z - mref), p7 = __expf(sb.w - mref);
      float psum = ((p0 + p1) + (p2 + p3)) + ((p4 + p5) + (p6 + p7));
      psum = dppadd1(psum); psum = dppadd2(psum); psum += __shfl_xor(psum, 4);
      union { ushort u[8]; short8 v; } pb;
      pb.u[0] = f2bf(p0); pb.u[1] = f2bf(p1); pb.u[2] = f2bf(p2); pb.u[3] = f2bf(p3);
      pb.u[4] = f2bf(p4); pb.u[5] = f2bf(p5); pb.u[6] = f2bf(p6); pb.u[7] = f2bf(p7);
      *(short8*)(PsB + row * 128 + ((ic ^ (row & 7)) << 4)) = pb.v;
      if (ic == 0) {
        float sc = grow ? __expf(mold - mx) : 1.0f;
        resc[row] = sc;
        lstate[row] = lstate[row] * sc + psum;
        if (grow) { mstate[row] = mx; gflag[cur] = 1; }
      }
    }
    VM0;        // V(t) + K(t+1) certified landed (cross-wave safe after B3)
    BARRIER();  // B3: P/resc/gflag visible + staged tiles certified
    gf = gflag[cur];
  }

  doPV(gf);  // final PV (V(NT-1) certified at last B3)

  // epilogue: O / l
#pragma unroll
  for (int mf = 0; mf < 4; ++mf) {
#pragma unroll
    for (int r = 0; r < 4; ++r) {
      int row = mf * 16 + lg * 4 + r;
      float inv = 1.0f / lstate[row];
      float* op = Out + ((size_t)b * SREF + q0 + row) * 512 + wid * 64;
#pragma unroll
      for (int nf = 0; nf < 4; ++nf) op[nf * 16 + lr] = oacc[mf][nf][r] * inv;
    }
  }
}

extern "C" void kernel_launch(void* const* d_in, const int* in_sizes, int n_in,
                              void* d_out, int out_size, void* d_ws, size_t ws_size,
                              hipStream_t stream) {
  const float* X  = (const float*)d_in[0];
  const float* Wq = (const float*)d_in[1];
  const float* bq = (const float*)d_in[2];
  const float* Wk = (const float*)d_in[3];
  const float* bk = (const float*)d_in[4];
  const float* Wv = (const float*)d_in[5];
  const float* bv = (const float*)d_in[6];
  ushort* ws = (ushort*)d_ws;
  float* out = (float*)d_out;

  // d_out doubles as scratch for bf16 X and W^T until attn overwrites it.
  ushort* Xb = (ushort*)d_out;
  ushort* Wt = Xb + (size_t)M_ * D_;

  prep_kernel<<<dim3(4096 + 192), dim3(256), 0, stream>>>(X, Wq, Wk, Wv, Xb, Wt);

  dim3 g1(M_ / 64, D_ / 64), b1(256);
  qkv_kernel<<<g1, b1, 0, stream>>>(Xb, Wt, bq, bk, bv, ws);

  attn_kernel<<<dim3(SREF / QT, 8), dim3(512), 0, stream>>>(
      ws, ws + (size_t)M_ * D_, ws + 2 * (size_t)M_ * D_, out);
}